// Round 7
// baseline (5992.329 us; speedup 1.0000x reference)
//
#include <hip/hip_runtime.h>
#include <cstdint>
#include <cstddef>
#include <climits>

// DacResidualVectorQuantize on MI355X. Exact-class (f64-internal, f32
// materialization) chain + CLUSTER-ARGMIN: lowest index among codes whose
// exact dist is within TOL (~2 f32 ulp) of the minimum. This reproduces
// numpy-f32 argmin tie behavior (ties -> first index) without needing the
// reference's bit-exact op ordering.

#define NCOL 32768
#define QBASE 33554432ull  // 16*1024*2048 (quant region == residual storage)
#define PREF32 2e-5f       // f32 prefilter band (score units)
#define TOLS 1.25e-7       // = TOL_dist/2 (dist tolerance 2.5e-7)
#define CAP 6

// f32 round of exact sum of 8 f32 values
__device__ __forceinline__ float s8_exact(const float* x) {
  double a = 0.0;
#pragma unroll
  for (int k = 0; k < 8; ++k) a += (double)x[k];
  return (float)a;
}

// f32 round of exact dot of two 8-length f32 vectors
__device__ __forceinline__ float dot8_exact(const float* x, const float* y) {
  double a = 0.0;
#pragma unroll
  for (int k = 0; k < 8; ++k) a = fma((double)x[k], (double)y[k], a);
  return (float)a;
}

// -------------------------------------------------------------- K1: prep
__global__ __launch_bounds__(256) void k_prep(
    const float* __restrict__ in_v, const float* __restrict__ in_g,
    const float* __restrict__ out_v, const float* __restrict__ out_g,
    const float* __restrict__ cbk, float* __restrict__ w_inT,
    float* __restrict__ w_outT, float* __restrict__ cnf,
    float* __restrict__ cn2, double* __restrict__ loss_acc) {
#pragma clang fp contract(off)
  int id = blockIdx.x * 256 + threadIdx.x;
  if (id == 0) loss_acc[0] = 0.0;
  if (id < 72) {
    int i = id >> 3, o = id & 7;
    const float* v = in_v + (size_t)id * 1024;
    double n2 = 0.0;
    for (int d = 0; d < 1024; ++d) {
      float sqv = v[d] * v[d];
      n2 += (double)sqv;
    }
    float n2f = (float)n2;
    float nrm = (float)sqrt((double)n2f);
    float g = in_g[id];
    for (int d = 0; d < 1024; ++d) {
      float gv = g * v[d];
      float w = gv / nrm;
      w_inT[((size_t)i * 1024 + d) * 8 + o] = w;
    }
  } else if (id < 72 + 9216) {
    int r = id - 72;  // (i,d) row of out_v [9][1024][8]
    const float* v = out_v + (size_t)r * 8;
    float sq[8];
#pragma unroll
    for (int k = 0; k < 8; ++k) sq[k] = v[k] * v[k];
    float n2f = s8_exact(sq);
    float nrm = (float)sqrt((double)n2f);
    float g = out_g[r];
#pragma unroll
    for (int k = 0; k < 8; ++k) {
      float gv = g * v[k];
      w_outT[(size_t)r * 8 + k] = gv / nrm;
    }
  } else if (id < 72 + 9216 + 9216) {
    int r = id - 72 - 9216;  // code row (i*1024+c)
    const float* v = cbk + (size_t)r * 8;
    float sq[8];
#pragma unroll
    for (int k = 0; k < 8; ++k) sq[k] = v[k] * v[k];
    float n2f = s8_exact(sq);
    float nrm = (float)sqrt((double)n2f);
    float den = fmaxf(nrm, 1e-12f);
    float cn[8], c2[8];
#pragma unroll
    for (int k = 0; k < 8; ++k) {
      cn[k] = v[k] / den;
      cnf[(size_t)r * 8 + k] = cn[k];
      c2[k] = cn[k] * cn[k];
    }
    cn2[r] = s8_exact(c2);
  }
}

// --------------------------------- K2: stage-0 z_e fold (residual == h)
__global__ __launch_bounds__(64) void k_z0(
    const float* __restrict__ h, const float* __restrict__ w_inT,
    float* __restrict__ zebuf) {
#pragma clang fp contract(off)
  int col = blockIdx.x * 64 + threadIdx.x;
  int b = col >> 11, t = col & 2047;
  const float* rbase = h + (size_t)b * 1024 * 2048 + t;
  double acc[8] = {0, 0, 0, 0, 0, 0, 0, 0};
  for (int d = 0; d < 1024; ++d) {
    double r = (double)rbase[(size_t)d * 2048];
    const float* w = &w_inT[(size_t)d * 8];
#pragma unroll
    for (int o = 0; o < 8; ++o) acc[o] = fma((double)w[o], r, acc[o]);
  }
#pragma unroll
  for (int o = 0; o < 8; ++o) zebuf[(size_t)o * NCOL + col] = (float)acc[o];
}

// -------- K3: select with cluster-argmin (f32 prefilter + f64 rescore)
// score s = en.cn - |cn|^2/2 (maximize); dist = t1 - 2s (monotone).
// Final pick: lowest index among {c : s64_c >= s64_max - TOLS}.
__global__ __launch_bounds__(256) void k_sel(
    const float* __restrict__ zebuf, const float* __restrict__ in_b,
    const float* __restrict__ cnf, const float* __restrict__ cn2,
    const float* __restrict__ cbk, int i, int nq, float* __restrict__ out,
    float* __restrict__ zqst, double* __restrict__ loss_acc) {
#pragma clang fp contract(off)
  __shared__ float m32[4][64];
  __shared__ double m64[4][64];
  __shared__ int mix[4][64];
  int tid = threadIdx.x;
  int lane = tid & 63;
  int chunk = tid >> 6;
  int col = blockIdx.x * 64 + lane;
  int b = col >> 11, t = col & 2047;

  float z[8];
#pragma unroll
  for (int o = 0; o < 8; ++o)
    z[o] = zebuf[(size_t)o * NCOL + col] + in_b[i * 8 + o];  // add eqn f32

  float sq[8];
#pragma unroll
  for (int k = 0; k < 8; ++k) sq[k] = z[k] * z[k];
  float n2f = s8_exact(sq);
  float nrm = (float)sqrt((double)n2f);
  float den = fmaxf(nrm, 1e-12f);
  float en[8];
#pragma unroll
  for (int k = 0; k < 8; ++k) en[k] = z[k] / den;  // div eqn f32

  const float* cb = cnf + ((size_t)i * 1024 + chunk * 256) * 8;
  const float* c2 = cn2 + (size_t)i * 1024 + chunk * 256;

  // ---- PASS 1: f32 prefilter scan (order-free, FMA ok)
  float b32 = -__builtin_inff();
  for (int c = 0; c < 256; ++c) {
    const float* cp = cb + (size_t)c * 8;
    float s = fmaf(en[0], cp[0], -0.5f * c2[c]);
#pragma unroll
    for (int k = 1; k < 8; ++k) s = fmaf(en[k], cp[k], s);
    b32 = fmaxf(b32, s);
  }
  m32[chunk][lane] = b32;
  __syncthreads();
  float g32 = m32[0][lane];
#pragma unroll
  for (int ch = 1; ch < 4; ++ch) g32 = fmaxf(g32, m32[ch][lane]);
  float cut32 = g32 - PREF32;

  // ---- PASS 2: rescan; f64-rescore prequalified codes, cache them
  double cs[CAP];
  int ci[CAP];
  int cnt = 0;
  double b64 = -1e300;
  for (int c = 0; c < 256; ++c) {
    const float* cp = cb + (size_t)c * 8;
    float s = fmaf(en[0], cp[0], -0.5f * c2[c]);
#pragma unroll
    for (int k = 1; k < 8; ++k) s = fmaf(en[k], cp[k], s);
    if (s >= cut32) {
      double a = 0.0, q = 0.0;
#pragma unroll
      for (int k = 0; k < 8; ++k) {
        double cd = (double)cp[k];
        a = fma((double)en[k], cd, a);
        q = fma(cd, cd, q);
      }
      double s64 = a - 0.5 * q;
      if (s64 > b64) b64 = s64;
      if (cnt < CAP) {
        cs[cnt] = s64;
        ci[cnt] = chunk * 256 + c;
        ++cnt;
      } else {
        int wm = 0;
        double wv = cs[0];
#pragma unroll
        for (int u = 1; u < CAP; ++u)
          if (cs[u] < wv) { wv = cs[u]; wm = u; }
        if (s64 > wv) { cs[wm] = s64; ci[wm] = chunk * 256 + c; }
      }
    }
  }
  m64[chunk][lane] = b64;
  __syncthreads();
  double g64 = m64[0][lane];
#pragma unroll
  for (int ch = 1; ch < 4; ++ch) g64 = fmax(g64, m64[ch][lane]);
  double cut64 = g64 - TOLS;

  // ---- local: lowest cached index within TOLS of global max
  int loc = INT_MAX;
  for (int u = 0; u < cnt; ++u)
    if (cs[u] >= cut64 && ci[u] < loc) loc = ci[u];
  mix[chunk][lane] = loc;
  __syncthreads();

  if (chunk == 0) {
    int g = mix[0][lane];
#pragma unroll
    for (int ch = 1; ch < 4; ++ch) g = min(g, mix[ch][lane]);
    size_t idx_base = QBASE;
    size_t lat_base = idx_base + (size_t)16 * nq * 2048;
    out[idx_base + ((size_t)b * nq + i) * 2048 + t] = (float)g;
#pragma unroll
    for (int o = 0; o < 8; ++o)
      out[lat_base + ((size_t)b * (nq * 8) + (i * 8 + o)) * 2048 + t] = z[o];
    const float* zp = &cbk[((size_t)i * 1024 + g) * 8];
    double lsum = 0.0;
#pragma unroll
    for (int k = 0; k < 8; ++k) {
      float zq = zp[k];
      float dlt = zq - z[k];
      float st = z[k] + dlt;  // straight-through, two roundings
      zqst[(size_t)k * NCOL + col] = st;
      float df = z[k] - zq;
      lsum += (double)df * (double)df;
    }
#pragma unroll
    for (int off = 1; off < 64; off <<= 1) lsum += __shfl_xor(lsum, off, 64);
    if (lane == 0) atomicAdd(loss_acc, lsum);
  }
}

// ------- K4: update: q = f32(f64 dot8) + b; residual f32; fused next z_e
__global__ __launch_bounds__(64) void k_upd(
    const float* __restrict__ h, const float* __restrict__ w_outT,
    const float* __restrict__ out_b, const float* __restrict__ w_inT,
    const float* __restrict__ zqst, int i, int nq, float* __restrict__ resid,
    float* __restrict__ zebuf) {
#pragma clang fp contract(off)
  int col = blockIdx.x * 64 + threadIdx.x;
  int b = col >> 11, t = col & 2047;
  float s[8];
#pragma unroll
  for (int k = 0; k < 8; ++k) s[k] = zqst[(size_t)k * NCOL + col];
  const float* wo = w_outT + (size_t)i * 1024 * 8;
  const float* bo = out_b + (size_t)i * 1024;
  const float* wn = w_inT + (size_t)(i + 1 < 9 ? i + 1 : 0) * 1024 * 8;
  bool last = (i == nq - 1);
  bool first = (i == 0);
  size_t cbase = (size_t)b * 1024 * 2048 + t;

  double zacc[8] = {0, 0, 0, 0, 0, 0, 0, 0};
  for (int d = 0; d < 1024; ++d) {
    const float* wr = &wo[(size_t)d * 8];
    float qe = dot8_exact(wr, s);
    float q = qe + bo[d];
    size_t adr = cbase + (size_t)d * 2048;
    float r = first ? h[adr] : resid[adr];
    float rn = r - q;
    if (last) {
      float hv = h[adr];
      resid[adr] = hv - rn;  // quant = h - residual_final
    } else {
      resid[adr] = rn;
      const float* wz = &wn[(size_t)d * 8];
      double rd = (double)rn;
#pragma unroll
      for (int o = 0; o < 8; ++o) zacc[o] = fma((double)wz[o], rd, zacc[o]);
    }
  }
  if (!last)
#pragma unroll
    for (int o = 0; o < 8; ++o) zebuf[(size_t)o * NCOL + col] = (float)zacc[o];
}

// --------------------------------------------------------- K5: losses
__global__ void k_fin(const double* __restrict__ loss_acc, int nq,
                      float* __restrict__ out) {
  if (threadIdx.x == 0 && blockIdx.x == 0) {
    float v = (float)(loss_acc[0] / 262144.0);  // B*CD*T
    size_t base = QBASE + (size_t)16 * nq * 2048 + (size_t)16 * nq * 8 * 2048;
    out[base] = v;
    out[base + 1] = v;
  }
}

// ------------------------------------------------------------------ launch
extern "C" void kernel_launch(void* const* d_in, const int* in_sizes, int n_in,
                              void* d_out, int out_size, void* d_ws,
                              size_t ws_size, hipStream_t stream) {
  (void)in_sizes; (void)n_in; (void)ws_size;
  const float* h     = (const float*)d_in[0];
  const float* in_v  = (const float*)d_in[1];
  const float* in_g  = (const float*)d_in[2];
  const float* in_b  = (const float*)d_in[3];
  const float* out_v = (const float*)d_in[4];
  const float* out_g = (const float*)d_in[5];
  const float* out_b = (const float*)d_in[6];
  const float* cbk   = (const float*)d_in[7];
  float* out = (float*)d_out;
  char* ws = (char*)d_ws;

  long long nq_ll = ((long long)out_size - (long long)QBASE - 2) / 294912LL;
  int nq = (int)nq_ll;
  if (nq < 1) nq = 1;
  if (nq > 9) nq = 9;

  size_t off = 0;
  auto alloc = [&](size_t bytes) {
    size_t o = off;
    off += (bytes + 255) & ~(size_t)255;
    return o;
  };
  float*  w_inT  = (float*)(ws + alloc((size_t)9 * 1024 * 8 * 4));
  float*  w_outT = (float*)(ws + alloc((size_t)9 * 1024 * 8 * 4));
  float*  cnf    = (float*)(ws + alloc((size_t)9 * 1024 * 8 * 4));
  float*  cn2    = (float*)(ws + alloc((size_t)9 * 1024 * 4));
  float*  zebuf  = (float*)(ws + alloc((size_t)8 * NCOL * 4));
  float*  zqst   = (float*)(ws + alloc((size_t)8 * NCOL * 4));
  double* lossa  = (double*)(ws + alloc(256));

  float* resid = out;  // quant region doubles as residual storage

  k_prep<<<dim3(73), 256, 0, stream>>>(in_v, in_g, out_v, out_g, cbk, w_inT,
                                       w_outT, cnf, cn2, lossa);
  k_z0<<<dim3(512), 64, 0, stream>>>(h, w_inT, zebuf);
  for (int i = 0; i < nq; ++i) {
    k_sel<<<dim3(512), 256, 0, stream>>>(zebuf, in_b, cnf, cn2, cbk, i, nq,
                                         out, zqst, lossa);
    k_upd<<<dim3(512), 64, 0, stream>>>(h, w_outT, out_b, w_inT, zqst, i, nq,
                                        resid, zebuf);
  }
  k_fin<<<1, 64, 0, stream>>>(lossa, nq, out);
}

// Round 8
// 1731.195 us; speedup vs baseline: 3.4614x; 3.4614x over previous
//
#include <hip/hip_runtime.h>
#include <cstdint>
#include <cstddef>
#include <climits>

// DacResidualVectorQuantize on MI355X. Exact-class (f64-internal, f32
// materialization) chain + cluster-argmin (lowest index within ~2 f32 ulp of
// the exact min) — PASSED R7 with all indices exact. R8: parallelize the
// residual-update/fold pipeline (was 2 waves/CU, 4.9% HBM): d-chunked blocks,
// float2 cols, LDS-staged weights, f64 partials + ordered reduce.

#define NCOL 32768
#define QBASE 33554432ull  // 16*1024*2048 (quant region == residual storage)
#define PREF32 2e-5f       // f32 prefilter band (score units)
#define TOLS 1.25e-7       // score tolerance (= dist tol 2.5e-7 / 2)
#define CAP 6
#define DCH 128            // d-rows per chunk-block
#define NCH 8              // 1024 / DCH

// f32 round of exact sum of 8 f32 values
__device__ __forceinline__ float s8_exact(const float* x) {
  double a = 0.0;
#pragma unroll
  for (int k = 0; k < 8; ++k) a += (double)x[k];
  return (float)a;
}

// f32 round of exact dot of two 8-length f32 vectors
__device__ __forceinline__ float dot8_exact(const float* x, const float* y) {
  double a = 0.0;
#pragma unroll
  for (int k = 0; k < 8; ++k) a = fma((double)x[k], (double)y[k], a);
  return (float)a;
}

// -------------------------------------------------------------- K1: prep
__global__ __launch_bounds__(256) void k_prep(
    const float* __restrict__ in_v, const float* __restrict__ in_g,
    const float* __restrict__ out_v, const float* __restrict__ out_g,
    const float* __restrict__ cbk, float* __restrict__ w_inT,
    float* __restrict__ w_outT, float* __restrict__ cnf,
    float* __restrict__ cn2, double* __restrict__ loss_acc) {
#pragma clang fp contract(off)
  int id = blockIdx.x * 256 + threadIdx.x;
  if (id == 0) loss_acc[0] = 0.0;
  if (id < 72) {
    int i = id >> 3, o = id & 7;
    const float* v = in_v + (size_t)id * 1024;
    double n2 = 0.0;
    for (int d = 0; d < 1024; ++d) {
      float sqv = v[d] * v[d];
      n2 += (double)sqv;
    }
    float n2f = (float)n2;
    float nrm = (float)sqrt((double)n2f);
    float g = in_g[id];
    for (int d = 0; d < 1024; ++d) {
      float gv = g * v[d];
      float w = gv / nrm;
      w_inT[((size_t)i * 1024 + d) * 8 + o] = w;
    }
  } else if (id < 72 + 9216) {
    int r = id - 72;  // (i,d) row of out_v [9][1024][8]
    const float* v = out_v + (size_t)r * 8;
    float sq[8];
#pragma unroll
    for (int k = 0; k < 8; ++k) sq[k] = v[k] * v[k];
    float n2f = s8_exact(sq);
    float nrm = (float)sqrt((double)n2f);
    float g = out_g[r];
#pragma unroll
    for (int k = 0; k < 8; ++k) {
      float gv = g * v[k];
      w_outT[(size_t)r * 8 + k] = gv / nrm;
    }
  } else if (id < 72 + 9216 + 9216) {
    int r = id - 72 - 9216;  // code row (i*1024+c)
    const float* v = cbk + (size_t)r * 8;
    float sq[8];
#pragma unroll
    for (int k = 0; k < 8; ++k) sq[k] = v[k] * v[k];
    float n2f = s8_exact(sq);
    float nrm = (float)sqrt((double)n2f);
    float den = fmaxf(nrm, 1e-12f);
    float cn[8], c2[8];
#pragma unroll
    for (int k = 0; k < 8; ++k) {
      cn[k] = v[k] / den;
      cnf[(size_t)r * 8 + k] = cn[k];
      c2[k] = cn[k] * cn[k];
    }
    cn2[r] = s8_exact(c2);
  }
}

// ---------------- K2: initial z_e fold partials from h (stage 0 weights)
// grid (64, NCH) x 256 thr; thread = 2 cols (float2), DCH d-rows.
__global__ __launch_bounds__(256) void k_fold(
    const float* __restrict__ h, const float* __restrict__ w_inT,
    double* __restrict__ part) {
#pragma clang fp contract(off)
  __shared__ float wl[DCH][8];
  int tid = threadIdx.x;
  int dq = blockIdx.y, d0 = dq * DCH;
  const float* w = w_inT + (size_t)d0 * 8;
  for (int u = tid; u < DCH * 8; u += 256) wl[u >> 3][u & 7] = w[u];
  __syncthreads();

  int col0 = blockIdx.x * 512 + tid * 2;
  int b = col0 >> 11, t = col0 & 2047;
  size_t base = (size_t)b * 1024 * 2048 + (size_t)d0 * 2048 + t;
  double za0[8] = {0, 0, 0, 0, 0, 0, 0, 0};
  double za1[8] = {0, 0, 0, 0, 0, 0, 0, 0};
  for (int dd = 0; dd < DCH; ++dd) {
    float2 rv = *(const float2*)&h[base + (size_t)dd * 2048];
    double r0 = (double)rv.x, r1 = (double)rv.y;
#pragma unroll
    for (int o = 0; o < 8; ++o) {
      double wv = (double)wl[dd][o];
      za0[o] = fma(wv, r0, za0[o]);
      za1[o] = fma(wv, r1, za1[o]);
    }
  }
#pragma unroll
  for (int o = 0; o < 8; ++o) {
    double2 pv = {za0[o], za1[o]};
    *(double2*)&part[((size_t)(o * NCH + dq)) * NCOL + col0] = pv;
  }
}

// ---------------- K2b: reduce NCH partials (ascending order) -> zebuf f32
__global__ __launch_bounds__(256) void k_zred(
    const double* __restrict__ part, float* __restrict__ zebuf) {
  int id = blockIdx.x * 256 + threadIdx.x;  // [0, 8*NCOL)
  int o = id >> 15;
  int col = id & (NCOL - 1);
  double s = 0.0;
#pragma unroll
  for (int q = 0; q < NCH; ++q)
    s += part[((size_t)(o * NCH + q)) * NCOL + col];
  zebuf[(size_t)o * NCOL + col] = (float)s;
}

// -------- K3: select with cluster-argmin (f32 prefilter + f64 rescore)
__global__ __launch_bounds__(256) void k_sel(
    const float* __restrict__ zebuf, const float* __restrict__ in_b,
    const float* __restrict__ cnf, const float* __restrict__ cn2,
    const float* __restrict__ cbk, int i, int nq, float* __restrict__ out,
    float* __restrict__ zqst, double* __restrict__ loss_acc) {
#pragma clang fp contract(off)
  __shared__ float m32[4][64];
  __shared__ double m64[4][64];
  __shared__ int mix[4][64];
  int tid = threadIdx.x;
  int lane = tid & 63;
  int chunk = tid >> 6;
  int col = blockIdx.x * 64 + lane;
  int b = col >> 11, t = col & 2047;

  float z[8];
#pragma unroll
  for (int o = 0; o < 8; ++o)
    z[o] = zebuf[(size_t)o * NCOL + col] + in_b[i * 8 + o];  // add eqn f32

  float sq[8];
#pragma unroll
  for (int k = 0; k < 8; ++k) sq[k] = z[k] * z[k];
  float n2f = s8_exact(sq);
  float nrm = (float)sqrt((double)n2f);
  float den = fmaxf(nrm, 1e-12f);
  float en[8];
#pragma unroll
  for (int k = 0; k < 8; ++k) en[k] = z[k] / den;  // div eqn f32

  const float* cb = cnf + ((size_t)i * 1024 + chunk * 256) * 8;
  const float* c2 = cn2 + (size_t)i * 1024 + chunk * 256;

  // ---- PASS 1: f32 prefilter scan (order-free, FMA ok)
  float b32 = -__builtin_inff();
  for (int c = 0; c < 256; ++c) {
    const float* cp = cb + (size_t)c * 8;
    float s = fmaf(en[0], cp[0], -0.5f * c2[c]);
#pragma unroll
    for (int k = 1; k < 8; ++k) s = fmaf(en[k], cp[k], s);
    b32 = fmaxf(b32, s);
  }
  m32[chunk][lane] = b32;
  __syncthreads();
  float g32 = m32[0][lane];
#pragma unroll
  for (int ch = 1; ch < 4; ++ch) g32 = fmaxf(g32, m32[ch][lane]);
  float cut32 = g32 - PREF32;

  // ---- PASS 2: rescan; f64-rescore prequalified codes, cache them
  double cs[CAP];
  int ci[CAP];
  int cnt = 0;
  double b64 = -1e300;
  for (int c = 0; c < 256; ++c) {
    const float* cp = cb + (size_t)c * 8;
    float s = fmaf(en[0], cp[0], -0.5f * c2[c]);
#pragma unroll
    for (int k = 1; k < 8; ++k) s = fmaf(en[k], cp[k], s);
    if (s >= cut32) {
      double a = 0.0, q = 0.0;
#pragma unroll
      for (int k = 0; k < 8; ++k) {
        double cd = (double)cp[k];
        a = fma((double)en[k], cd, a);
        q = fma(cd, cd, q);
      }
      double s64 = a - 0.5 * q;
      if (s64 > b64) b64 = s64;
      if (cnt < CAP) {
        cs[cnt] = s64;
        ci[cnt] = chunk * 256 + c;
        ++cnt;
      } else {
        int wm = 0;
        double wv = cs[0];
#pragma unroll
        for (int u = 1; u < CAP; ++u)
          if (cs[u] < wv) { wv = cs[u]; wm = u; }
        if (s64 > wv) { cs[wm] = s64; ci[wm] = chunk * 256 + c; }
      }
    }
  }
  m64[chunk][lane] = b64;
  __syncthreads();
  double g64 = m64[0][lane];
#pragma unroll
  for (int ch = 1; ch < 4; ++ch) g64 = fmax(g64, m64[ch][lane]);
  double cut64 = g64 - TOLS;

  int loc = INT_MAX;
  for (int u = 0; u < cnt; ++u)
    if (cs[u] >= cut64 && ci[u] < loc) loc = ci[u];
  mix[chunk][lane] = loc;
  __syncthreads();

  if (chunk == 0) {
    int g = mix[0][lane];
#pragma unroll
    for (int ch = 1; ch < 4; ++ch) g = min(g, mix[ch][lane]);
    size_t idx_base = QBASE;
    size_t lat_base = idx_base + (size_t)16 * nq * 2048;
    out[idx_base + ((size_t)b * nq + i) * 2048 + t] = (float)g;
#pragma unroll
    for (int o = 0; o < 8; ++o)
      out[lat_base + ((size_t)b * (nq * 8) + (i * 8 + o)) * 2048 + t] = z[o];
    const float* zp = &cbk[((size_t)i * 1024 + g) * 8];
    double lsum = 0.0;
#pragma unroll
    for (int k = 0; k < 8; ++k) {
      float zq = zp[k];
      float dlt = zq - z[k];
      float st = z[k] + dlt;  // straight-through, two roundings
      zqst[(size_t)k * NCOL + col] = st;
      float df = z[k] - zq;
      lsum += (double)df * (double)df;
    }
#pragma unroll
    for (int off = 1; off < 64; off <<= 1) lsum += __shfl_xor(lsum, off, 64);
    if (lane == 0) atomicAdd(loss_acc, lsum);
  }
}

// ------- K4: parallel update: q = f32(f64 dot8) + b; residual f32;
//          f64 z_e partials for next stage. grid (64, NCH) x 256 thr.
//          Last stage writes quant = h - resid_new (no partials).
__global__ __launch_bounds__(256) void k_upd(
    const float* __restrict__ h, const float* __restrict__ w_outT,
    const float* __restrict__ out_b, const float* __restrict__ w_inT,
    const float* __restrict__ zqst, int i, int nq, float* __restrict__ resid,
    double* __restrict__ part) {
#pragma clang fp contract(off)
  __shared__ float wol[DCH][8];
  __shared__ float bol[DCH];
  __shared__ float wnl[DCH][8];
  int tid = threadIdx.x;
  int dq = blockIdx.y, d0 = dq * DCH;
  bool last = (i == nq - 1);
  bool first = (i == 0);
  const float* wo = w_outT + ((size_t)i * 1024 + d0) * 8;
  const float* bo = out_b + (size_t)i * 1024 + d0;
  const float* wn = w_inT + ((size_t)(last ? i : i + 1) * 1024 + d0) * 8;
  for (int u = tid; u < DCH * 8; u += 256) {
    wol[u >> 3][u & 7] = wo[u];
    wnl[u >> 3][u & 7] = last ? 0.f : wn[u];
  }
  for (int u = tid; u < DCH; u += 256) bol[u] = bo[u];
  __syncthreads();

  int col0 = blockIdx.x * 512 + tid * 2;
  int b = col0 >> 11, t = col0 & 2047;
  float s0[8], s1[8];
#pragma unroll
  for (int k = 0; k < 8; ++k) {
    float2 sv = *(const float2*)&zqst[(size_t)k * NCOL + col0];
    s0[k] = sv.x;
    s1[k] = sv.y;
  }
  double za0[8] = {0, 0, 0, 0, 0, 0, 0, 0};
  double za1[8] = {0, 0, 0, 0, 0, 0, 0, 0};
  size_t base = (size_t)b * 1024 * 2048 + (size_t)d0 * 2048 + t;

  for (int dd = 0; dd < DCH; ++dd) {
    double a0 = 0.0, a1 = 0.0;
#pragma unroll
    for (int k = 0; k < 8; ++k) {
      double wv = (double)wol[dd][k];
      a0 = fma(wv, (double)s0[k], a0);
      a1 = fma(wv, (double)s1[k], a1);
    }
    float qe0 = (float)a0, qe1 = (float)a1;  // dot_general -> f32 cast
    float bias = bol[dd];
    float q0 = qe0 + bias, q1 = qe1 + bias;  // add eqn f32
    size_t adr = base + (size_t)dd * 2048;
    float2 rv;
    if (first)
      rv = *(const float2*)&h[adr];
    else
      rv = *(const float2*)&resid[adr];
    float rn0 = rv.x - q0, rn1 = rv.y - q1;  // sub eqn f32
    if (last) {
      float2 hv = *(const float2*)&h[adr];
      float2 qq = {hv.x - rn0, hv.y - rn1};  // quant = h - residual_final
      *(float2*)&resid[adr] = qq;
    } else {
      float2 rr = {rn0, rn1};
      *(float2*)&resid[adr] = rr;
      double r0 = (double)rn0, r1 = (double)rn1;
#pragma unroll
      for (int o = 0; o < 8; ++o) {
        double wv = (double)wnl[dd][o];
        za0[o] = fma(wv, r0, za0[o]);
        za1[o] = fma(wv, r1, za1[o]);
      }
    }
  }
  if (!last) {
#pragma unroll
    for (int o = 0; o < 8; ++o) {
      double2 pv = {za0[o], za1[o]};
      *(double2*)&part[((size_t)(o * NCH + dq)) * NCOL + col0] = pv;
    }
  }
}

// --------------------------------------------------------- K5: losses
__global__ void k_fin(const double* __restrict__ loss_acc, int nq,
                      float* __restrict__ out) {
  if (threadIdx.x == 0 && blockIdx.x == 0) {
    float v = (float)(loss_acc[0] / 262144.0);  // B*CD*T
    size_t base = QBASE + (size_t)16 * nq * 2048 + (size_t)16 * nq * 8 * 2048;
    out[base] = v;
    out[base + 1] = v;
  }
}

// ------------------------------------------------------------------ launch
extern "C" void kernel_launch(void* const* d_in, const int* in_sizes, int n_in,
                              void* d_out, int out_size, void* d_ws,
                              size_t ws_size, hipStream_t stream) {
  (void)in_sizes; (void)n_in; (void)ws_size;
  const float* h     = (const float*)d_in[0];
  const float* in_v  = (const float*)d_in[1];
  const float* in_g  = (const float*)d_in[2];
  const float* in_b  = (const float*)d_in[3];
  const float* out_v = (const float*)d_in[4];
  const float* out_g = (const float*)d_in[5];
  const float* out_b = (const float*)d_in[6];
  const float* cbk   = (const float*)d_in[7];
  float* out = (float*)d_out;
  char* ws = (char*)d_ws;

  long long nq_ll = ((long long)out_size - (long long)QBASE - 2) / 294912LL;
  int nq = (int)nq_ll;
  if (nq < 1) nq = 1;
  if (nq > 9) nq = 9;

  size_t off = 0;
  auto alloc = [&](size_t bytes) {
    size_t o = off;
    off += (bytes + 255) & ~(size_t)255;
    return o;
  };
  float*  w_inT  = (float*)(ws + alloc((size_t)9 * 1024 * 8 * 4));
  float*  w_outT = (float*)(ws + alloc((size_t)9 * 1024 * 8 * 4));
  float*  cnf    = (float*)(ws + alloc((size_t)9 * 1024 * 8 * 4));
  float*  cn2    = (float*)(ws + alloc((size_t)9 * 1024 * 4));
  float*  zebuf  = (float*)(ws + alloc((size_t)8 * NCOL * 4));
  float*  zqst   = (float*)(ws + alloc((size_t)8 * NCOL * 4));
  double* lossa  = (double*)(ws + alloc(256));
  double* part   = (double*)(ws + alloc((size_t)8 * NCH * NCOL * 8));

  float* resid = out;  // quant region doubles as residual storage

  k_prep<<<dim3(73), 256, 0, stream>>>(in_v, in_g, out_v, out_g, cbk, w_inT,
                                       w_outT, cnf, cn2, lossa);
  k_fold<<<dim3(64, NCH), 256, 0, stream>>>(h, w_inT, part);
  k_zred<<<dim3(1024), 256, 0, stream>>>(part, zebuf);
  for (int i = 0; i < nq; ++i) {
    k_sel<<<dim3(512), 256, 0, stream>>>(zebuf, in_b, cnf, cn2, cbk, i, nq,
                                         out, zqst, lossa);
    k_upd<<<dim3(64, NCH), 256, 0, stream>>>(h, w_outT, out_b, w_inT, zqst,
                                             i, nq, resid, part);
    if (i < nq - 1) k_zred<<<dim3(1024), 256, 0, stream>>>(part, zebuf);
  }
  k_fin<<<1, 64, 0, stream>>>(lossa, nq, out);
}